// Round 9
// baseline (165.715 us; speedup 1.0000x reference)
//
#include <hip/hip_runtime.h>
#include <hip/hip_bf16.h>

typedef __attribute__((ext_vector_type(8))) short short8;
typedef __attribute__((ext_vector_type(4))) float f32x4;

#define NBANDS 31
#define BB 8
#define CCH 2
#define FF 2049
#define TTS 512
#define OUTC 128
#define TCH 8196
#define EPSV 1e-5f

__constant__ int c_wid[NBANDS] = {
    25,25,25,25,25,25,25,25,25,25,
    50,50,50,50,50,50,50,50,50,50,50,50,
    100,100,100,100,100,100,100,100,
    399};
__constant__ int c_start[NBANDS] = {
    0,25,50,75,100,125,150,175,200,225,
    250,300,350,400,450,500,550,600,650,700,750,800,
    850,950,1050,1150,1250,1350,1450,1550,
    1650};
__constant__ int c_cumf[NBANDS + 1] = {
    0,1,2,3,4,5,6,7,8,9,
    10,12,14,16,18,20,22,24,26,28,30,32,
    34,38,42,46,50,54,58,62,
    66,79};
// K padded to multiple of 64
__constant__ int c_kpad[NBANDS] = {
    128,128,128,128,128,128,128,128,128,128,
    256,256,256,256,256,256,256,256,256,256,256,256,
    448,448,448,448,448,448,448,448,
    1600};
// element base of each band's packed (fragment-ordered, chunk-major) Wgamma panel
__constant__ int c_kbase[NBANDS] = {
    0,16384,32768,49152,65536,81920,98304,114688,131072,147456,
    163840,196608,229376,262144,294912,327680,360448,393216,425984,458752,491520,524288,
    557056,614400,671744,729088,786432,843776,901120,958464,
    1015808};
// heavy-first dispatch order (descending K)
__constant__ int c_order[NBANDS] = {
    30,22,23,24,25,26,27,28,29,
    10,11,12,13,14,15,16,17,18,19,20,21,
    0,1,2,3,4,5,6,7,8,9};

#define NSTATS 1264   // 79 chunks x 16 (b,cc)
#define NWPREP 248    // 31 bands x 8 o-groups
#define NWP2   992    // 31 bands x 32

__device__ inline unsigned short f2bf(float f) {
    __hip_bfloat16 h = __float2bfloat16(f);
    unsigned short u;
    __builtin_memcpy(&u, &h, 2);
    return u;
}

// ---------------- fused prep: stats partials | wgam/wcb | packed A panels ----------------
__global__ __launch_bounds__(256) void prep(const float* __restrict__ x,
                                            const float* __restrict__ W,
                                            const float* __restrict__ gamma,
                                            const float* __restrict__ beta,
                                            const float* __restrict__ bias,
                                            float* __restrict__ st,
                                            float* __restrict__ wgam,
                                            float* __restrict__ wcb,
                                            unsigned short* __restrict__ wgP) {
    __shared__ float s1[256], s2[256];
    const int bid = blockIdx.x;
    const int tid = threadIdx.x;

    if (bid < NSTATS) {
        // ---- stats role: partial sum/sumsq per (chunk, b, cc) ----
        int bx  = bid >> 4;              // chunk id [0,79)
        int ycc = bid & 15;              // (b<<1)|cc
        int band = 0;
        while (band + 1 < NBANDS && bx >= c_cumf[band + 1]) band++;
        int fc = bx - c_cumf[band];
        int b  = ycc >> 1;
        int cc = ycc & 1;
        int w = c_wid[band], s = c_start[band];
        int f0 = fc * 32;
        int rows = min(32, w - f0);

        const float4* p = (const float4*)(x + ((size_t)(b * CCH + cc) * FF + (s + f0)) * (TTS * 2));
        int n4 = rows * 256;
        float sum = 0.f, sq = 0.f;
        for (int i = tid; i < n4; i += 256) {
            float4 v = p[i];
            sum += v.x + v.y + v.z + v.w;
            sq  += v.x * v.x + v.y * v.y + v.z * v.z + v.w * v.w;
        }
        s1[tid] = sum; s2[tid] = sq;
        __syncthreads();
        for (int st_ = 128; st_ > 0; st_ >>= 1) {
            if (tid < st_) { s1[tid] += s1[tid + st_]; s2[tid] += s2[tid + st_]; }
            __syncthreads();
        }
        if (tid == 0) {
            float* dst = st + (size_t)(bx * 16 + ycc) * 2;
            dst[0] = s1[0];
            dst[1] = s2[0];
        }
    } else if (bid < NSTATS + NWPREP) {
        // ---- wprep role: wgam/wcb reductions ----
        int r = bid - NSTATS;
        int band = r >> 3;
        int off = 4 * c_start[band];
        int ch  = 4 * c_wid[band];
        int o = (r & 7) * 16 + (tid >> 4);
        int lane = tid & 15;
        const float* wrow = W + (size_t)o * TCH + off;
        float sg = 0.f, sb = 0.f;
        for (int c = lane; c < ch; c += 16) {
            float wv = wrow[c];
            sg += wv * gamma[off + c];
            sb += wv * beta[off + c];
        }
        for (int m = 8; m; m >>= 1) {
            sg += __shfl_down(sg, m, 16);
            sb += __shfl_down(sb, m, 16);
        }
        if (lane == 0) {
            wgam[band * OUTC + o] = sg;
            wcb[band * OUTC + o]  = sb + bias[band * OUTC + o];
        }
    } else {
        // ---- wprep2 role: pack W*gamma bf16 panels in per-lane MFMA fragment order:
        // [chunk][kk][m][lane][j8], lane=(o&15)+16*lg, k = chunk*64+kk*32+lg*8+j ----
        int r = bid - (NSTATS + NWPREP);
        int band = r % NBANDS;
        int gy   = r / NBANDS;           // 0..31
        int w = c_wid[band];
        int s4 = 4 * c_start[band];
        int Kpad = c_kpad[band];
        int base = c_kbase[band];
        int K4 = 4 * w;
        int N = OUTC * Kpad;
        for (int idx = gy * 256 + tid; idx < N; idx += 32 * 256) {
            int o = idx / Kpad;
            int k = idx - o * Kpad;
            float val = 0.f;
            if (k < K4) {
                int ri = k & 1, p = k >> 1;
                int cc = (p >= w) ? 1 : 0;
                int f = p - cc * w;
                int c = s4 + ri * 2 * w + cc * w + f;
                val = W[(size_t)o * TCH + c] * gamma[c];
            }
            int chunk = k >> 6, k6 = k & 63;
            int kk = k6 >> 5, kloc = k6 & 31;
            int lg = kloc >> 3, j = kloc & 7;
            int m = o >> 4, l15o = o & 15;
            int pos = chunk * 8192 + kk * 4096 + m * 512 + (l15o + 16 * lg) * 8 + j;
            wgP[base + pos] = f2bf(val);
        }
    }
}

// ---------------- MFMA GEMM: Y[o,t] = Wg[o,:]*h[:,t], norm fused in epilogue ----------------
// grid (32 = 8b x 4 ttile, 31 bands), 256 threads = 4 waves, each wave: M=128 x N=32.
// NO LDS, NO barriers: A fragments loaded direct from pre-packed L2-resident panel
// (lane-contiguous dwordx4), B gathered direct from x, B ping-pong reg prefetch.
__global__ __launch_bounds__(256, 3) void gemm_mfma(const float* __restrict__ x,
                                                    const unsigned short* __restrict__ wgP,
                                                    const float* __restrict__ st,
                                                    const float* __restrict__ wgam,
                                                    const float* __restrict__ wcb,
                                                    float* __restrict__ out) {
    const int band = c_order[blockIdx.y];
    const int b    = blockIdx.x >> 2;
    const int tt0  = (blockIdx.x & 3) * 128;
    const int w    = c_wid[band];
    const int s    = c_start[band];
    const int w2   = 2 * w;
    const int Kpad = c_kpad[band];
    const int nch  = Kpad >> 6;

    const int tid  = threadIdx.x;
    const int lane = tid & 63;
    const int wv   = tid >> 6;          // wave id (0..3) -> t-block of 32
    const int l15  = lane & 15;
    const int lg   = lane >> 4;         // 0..3

    // per-lane A panel base: fragment layout [chunk][kk][m][lane][8]
    const unsigned short* apl = wgP + c_kbase[band] + lane * 8;

    const float* xb = x + (size_t)b * (CCH * FF * TTS * 2);
    // per-lane t column (float index) for B loads: t = tt0 + wv*32 + nf*16 + l15
    const float* colbase = xb + (size_t)(tt0 + wv * 32 + l15) * 2;

    f32x4 acc[8][2] = {};
    float2 bA[16], bB[16];

    // issue 16 float2 loads of chunk c's B tile into dst (row clamped: A-zeros kill junk)
#define LOADB(c, dst) do {                                                     \
    _Pragma("unroll")                                                          \
    for (int kk = 0; kk < 2; ++kk)                                             \
        _Pragma("unroll")                                                      \
        for (int nf = 0; nf < 2; ++nf)                                         \
            _Pragma("unroll")                                                  \
            for (int j = 0; j < 4; ++j) {                                      \
                int p = 32 * (c) + 16 * kk + 4 * lg + j;                       \
                p = min(p, w2 - 1);                                            \
                int row = s + p + ((p >= w) ? (FF - w) : 0);                   \
                dst[kk * 8 + nf * 4 + j] =                                     \
                    *(const float2*)(colbase + (size_t)row * 1024 + nf * 32);  \
            }                                                                  \
} while (0)

    // A-frag direct loads + cvt + 32 MFMA for chunk c, B regs in br
#define COMPUTE(c, br) do {                                                    \
    _Pragma("unroll")                                                          \
    for (int kk = 0; kk < 2; ++kk) {                                           \
        const unsigned short* ap = apl + (size_t)(c) * 8192 + kk * 4096;       \
        short8 af[8];                                                          \
        _Pragma("unroll")                                                      \
        for (int m = 0; m < 8; ++m)                                            \
            af[m] = *(const short8*)(ap + m * 512);                            \
        short8 bf0, bf1;                                                       \
        _Pragma("unroll")                                                      \
        for (int j = 0; j < 4; ++j) {                                          \
            float2 v0 = br[kk * 8 + j];                                        \
            float2 v1 = br[kk * 8 + 4 + j];                                    \
            bf0[2 * j]     = (short)f2bf(v0.x);                                \
            bf0[2 * j + 1] = (short)f2bf(v0.y);                                \
            bf1[2 * j]     = (short)f2bf(v1.x);                                \
            bf1[2 * j + 1] = (short)f2bf(v1.y);                                \
        }                                                                      \
        _Pragma("unroll")                                                      \
        for (int m = 0; m < 8; ++m) {                                          \
            acc[m][0] = __builtin_amdgcn_mfma_f32_16x16x32_bf16(               \
                af[m], bf0, acc[m][0], 0, 0, 0);                               \
            acc[m][1] = __builtin_amdgcn_mfma_f32_16x16x32_bf16(               \
                af[m], bf1, acc[m][1], 0, 0, 0);                               \
        }                                                                      \
    }                                                                          \
} while (0)

    LOADB(0, bA);
    for (int c = 0; c < nch; c += 2) {
        if (c + 1 < nch) LOADB(c + 1, bB);
        COMPUTE(c, bA);
        if (c + 1 < nch) {
            if (c + 2 < nch) LOADB(c + 2, bA);
            COMPUTE(c + 1, bB);
        }
    }
#undef LOADB
#undef COMPUTE

    // inline finalize: reduce this (b,band)'s partials (<=13 chunks x 2 cc)
    float sum = 0.f, sq = 0.f;
    {
        int c0 = c_cumf[band], c1 = c_cumf[band + 1];
        for (int c = c0; c < c1; ++c) {
            const float* p0 = st + (size_t)(c * 16 + b * 2) * 2;
            sum += p0[0] + p0[2];
            sq  += p0[1] + p0[3];
        }
    }
    const float Nf = (float)(w * 2048);    // 4*w*512
    const float mu = sum / Nf;
    const float rs = rsqrtf(sq / Nf - mu * mu + EPSV);

#pragma unroll
    for (int m = 0; m < 8; ++m) {
#pragma unroll
        for (int r = 0; r < 4; ++r) {
            int o = m * 16 + lg * 4 + r;
            float wg = wgam[band * OUTC + o];
            float cb = wcb[band * OUTC + o];
            size_t rowoff = (((size_t)b * OUTC + o) * NBANDS + band) * TTS;
#pragma unroll
            for (int nf = 0; nf < 2; ++nf) {
                int t = tt0 + wv * 32 + nf * 16 + l15;
                out[rowoff + t] = rs * (acc[m][nf][r] - mu * wg) + cb;
            }
        }
    }
}

extern "C" void kernel_launch(void* const* d_in, const int* in_sizes, int n_in,
                              void* d_out, int out_size, void* d_ws, size_t ws_size,
                              hipStream_t stream) {
    const float* x     = (const float*)d_in[0];
    const float* gamma = (const float*)d_in[1];
    const float* beta  = (const float*)d_in[2];
    const float* W     = (const float*)d_in[3];
    const float* bias  = (const float*)d_in[4];
    float* out = (float*)d_out;
    float* ws  = (float*)d_ws;

    float* st_part = ws;            // 79*16*2 = 2528 floats (fully rewritten every call)
    float* wgam    = ws + 3072;     // 3968 floats
    float* wcb     = ws + 7168;     // 3968 floats
    unsigned short* wgP = (unsigned short*)(ws + 11264);  // 1220608 bf16 = 2.33 MB

    prep<<<NSTATS + NWPREP + NWP2, 256, 0, stream>>>(x, W, gamma, beta, bias,
                                                     st_part, wgam, wcb, wgP);
    gemm_mfma<<<dim3(32, NBANDS), 256, 0, stream>>>(x, wgP, st_part, wgam, wcb, out);
}

// Round 10
// 104.364 us; speedup vs baseline: 1.5879x; 1.5879x over previous
//
#include <hip/hip_runtime.h>
#include <hip/hip_bf16.h>

typedef __attribute__((ext_vector_type(8))) short short8;
typedef __attribute__((ext_vector_type(4))) float f32x4;

#define NBANDS 31
#define BB 8
#define CCH 2
#define FF 2049
#define TTS 512
#define OUTC 128
#define TCH 8196
#define EPSV 1e-5f

__constant__ int c_wid[NBANDS] = {
    25,25,25,25,25,25,25,25,25,25,
    50,50,50,50,50,50,50,50,50,50,50,50,
    100,100,100,100,100,100,100,100,
    399};
__constant__ int c_start[NBANDS] = {
    0,25,50,75,100,125,150,175,200,225,
    250,300,350,400,450,500,550,600,650,700,750,800,
    850,950,1050,1150,1250,1350,1450,1550,
    1650};
__constant__ int c_cumf[NBANDS + 1] = {
    0,1,2,3,4,5,6,7,8,9,
    10,12,14,16,18,20,22,24,26,28,30,32,
    34,38,42,46,50,54,58,62,
    66,79};
// K padded to multiple of 64
__constant__ int c_kpad[NBANDS] = {
    128,128,128,128,128,128,128,128,128,128,
    256,256,256,256,256,256,256,256,256,256,256,256,
    448,448,448,448,448,448,448,448,
    1600};
// element base of each band's packed (swizzled, chunk-major) Wgamma panel
__constant__ int c_kbase[NBANDS] = {
    0,16384,32768,49152,65536,81920,98304,114688,131072,147456,
    163840,196608,229376,262144,294912,327680,360448,393216,425984,458752,491520,524288,
    557056,614400,671744,729088,786432,843776,901120,958464,
    1015808};

// gemm grid y mapping: 5 band-30 K-splits first, then remaining bands heavy-first
#define NGY 35
__constant__ int g_band[NGY] = {
    30,30,30,30,30,
    22,23,24,25,26,27,28,29,
    10,11,12,13,14,15,16,17,18,19,20,21,
    0,1,2,3,4,5,6,7,8,9};
__constant__ int g_c0[NGY] = {
    0,5,10,15,20,
    0,0,0,0,0,0,0,0,
    0,0,0,0,0,0,0,0,0,0,0,0,
    0,0,0,0,0,0,0,0,0,0};

#define NSTATS 1264   // 79 chunks x 16 (b,cc)
#define NWPREP 248    // 31 bands x 8 o-groups
#define NWP2   992    // 31 bands x 32

__device__ inline unsigned short f2bf(float f) {
    __hip_bfloat16 h = __float2bfloat16(f);
    unsigned short u;
    __builtin_memcpy(&u, &h, 2);
    return u;
}

__device__ inline void gload_lds16(const void* g, void* l) {
    __builtin_amdgcn_global_load_lds((const __attribute__((address_space(1))) void*)g,
                                     (__attribute__((address_space(3))) void*)l, 16, 0, 0);
}

// ---------------- fused prep: stats partials | wgam/wcb | packed A panels ----------------
__global__ __launch_bounds__(256) void prep(const float* __restrict__ x,
                                            const float* __restrict__ W,
                                            const float* __restrict__ gamma,
                                            const float* __restrict__ beta,
                                            const float* __restrict__ bias,
                                            float* __restrict__ st,
                                            float* __restrict__ wgam,
                                            float* __restrict__ wcb,
                                            unsigned short* __restrict__ wgP) {
    __shared__ float s1[256], s2[256];
    const int bid = blockIdx.x;
    const int tid = threadIdx.x;

    if (bid < NSTATS) {
        // ---- stats role: partial sum/sumsq per (chunk, b, cc) ----
        int bx  = bid >> 4;              // chunk id [0,79)
        int ycc = bid & 15;              // (b<<1)|cc
        int band = 0;
        while (band + 1 < NBANDS && bx >= c_cumf[band + 1]) band++;
        int fc = bx - c_cumf[band];
        int b  = ycc >> 1;
        int cc = ycc & 1;
        int w = c_wid[band], s = c_start[band];
        int f0 = fc * 32;
        int rows = min(32, w - f0);

        const float4* p = (const float4*)(x + ((size_t)(b * CCH + cc) * FF + (s + f0)) * (TTS * 2));
        int n4 = rows * 256;
        float sum = 0.f, sq = 0.f;
        for (int i = tid; i < n4; i += 256) {
            float4 v = p[i];
            sum += v.x + v.y + v.z + v.w;
            sq  += v.x * v.x + v.y * v.y + v.z * v.z + v.w * v.w;
        }
        s1[tid] = sum; s2[tid] = sq;
        __syncthreads();
        for (int st_ = 128; st_ > 0; st_ >>= 1) {
            if (tid < st_) { s1[tid] += s1[tid + st_]; s2[tid] += s2[tid + st_]; }
            __syncthreads();
        }
        if (tid == 0) {
            float* dst = st + (size_t)(bx * 16 + ycc) * 2;
            dst[0] = s1[0];
            dst[1] = s2[0];
        }
    } else if (bid < NSTATS + NWPREP) {
        // ---- wprep role: wgam/wcb reductions ----
        int r = bid - NSTATS;
        int band = r >> 3;
        int off = 4 * c_start[band];
        int ch  = 4 * c_wid[band];
        int o = (r & 7) * 16 + (tid >> 4);
        int lane = tid & 15;
        const float* wrow = W + (size_t)o * TCH + off;
        float sg = 0.f, sb = 0.f;
        for (int c = lane; c < ch; c += 16) {
            float wv = wrow[c];
            sg += wv * gamma[off + c];
            sb += wv * beta[off + c];
        }
        for (int m = 8; m; m >>= 1) {
            sg += __shfl_down(sg, m, 16);
            sb += __shfl_down(sb, m, 16);
        }
        if (lane == 0) {
            wgam[band * OUTC + o] = sg;
            wcb[band * OUTC + o]  = sb + bias[band * OUTC + o];
        }
    } else {
        // ---- wprep2 role: pack W*gamma bf16 panels, chunk-major, slot-XOR swizzled ----
        int r = bid - (NSTATS + NWPREP);
        int band = r % NBANDS;
        int gy   = r / NBANDS;           // 0..31
        int w = c_wid[band];
        int s4 = 4 * c_start[band];
        int Kpad = c_kpad[band];
        int base = c_kbase[band];
        int K4 = 4 * w;
        int N = OUTC * Kpad;
        for (int idx = gy * 256 + tid; idx < N; idx += 32 * 256) {
            int o = idx / Kpad;
            int k = idx - o * Kpad;
            float val = 0.f;
            if (k < K4) {
                int ri = k & 1, p = k >> 1;
                int cc = (p >= w) ? 1 : 0;
                int f = p - cc * w;
                int c = s4 + ri * 2 * w + cc * w + f;
                val = W[(size_t)o * TCH + c] * gamma[c];
            }
            int slot = (k >> 3) & 7;
            int pos = (k >> 6) * 8192 + o * 64 + ((slot ^ (o & 7)) * 8) + (k & 7);
            wgP[base + pos] = f2bf(val);
        }
    }
}

// ---------------- MFMA GEMM: Y[o,t] = Wg[o,:]*h[:,t] ----------------
// grid (32 = 8b x 4 ttile, 35 = 5 band-30 K-splits + 30 bands), 256 threads = 4 waves.
// Band-30 splits write raw fp32 partials to ws; other bands fuse norm in epilogue.
__global__ __launch_bounds__(256) void gemm_mfma(const float* __restrict__ x,
                                                 const unsigned short* __restrict__ wgP,
                                                 const float* __restrict__ st,
                                                 const float* __restrict__ wgam,
                                                 const float* __restrict__ wcb,
                                                 float* __restrict__ part,
                                                 float* __restrict__ out) {
    const int band = g_band[blockIdx.y];
    const int c0   = g_c0[blockIdx.y];
    const int b    = blockIdx.x >> 2;
    const int tti  = blockIdx.x & 3;
    const int tt0  = tti * 128;
    const int w    = c_wid[band];
    const int s    = c_start[band];
    const int w2   = 2 * w;
    const int nch  = (band == 30) ? 5 : (c_kpad[band] >> 6);
    const unsigned short* wgA = wgP + c_kbase[band];

    __shared__ unsigned short lA[2][8192];   // 2 x 16KB: [o=128][k=64], slot-swizzled

    const int tid  = threadIdx.x;
    const int lane = tid & 63;
    const int wv   = tid >> 6;          // wave id (0..3) -> t-block of 32
    const int l15  = lane & 15;
    const int lg   = lane >> 4;         // 0..3

    const float* xb = x + (size_t)b * (CCH * FF * TTS * 2);
    // per-lane t column (float index) for B loads: t = tt0 + wv*32 + nf*16 + l15
    const float* colbase = xb + (size_t)(tt0 + wv * 32 + l15) * 2;

    f32x4 acc[8][2] = {};
    float2 bA[16], bB[16];

    // issue 16 float2 loads of chunk c's B tile into dst (row clamped: A-zeros kill junk)
#define LOADB(c, dst) do {                                                     \
    _Pragma("unroll")                                                          \
    for (int kk = 0; kk < 2; ++kk)                                             \
        _Pragma("unroll")                                                      \
        for (int nf = 0; nf < 2; ++nf)                                         \
            _Pragma("unroll")                                                  \
            for (int j = 0; j < 4; ++j) {                                      \
                int p = 32 * (c) + 16 * kk + 4 * lg + j;                       \
                p = min(p, w2 - 1);                                            \
                int row = s + p + ((p >= w) ? (FF - w) : 0);                   \
                dst[kk * 8 + nf * 4 + j] =                                     \
                    *(const float2*)(colbase + (size_t)row * 1024 + nf * 32);  \
            }                                                                  \
} while (0)

    // stage chunk c's A panel into LDS buffer buf (16KB via global_load_lds dwordx4)
#define STAGE(c, buf) do {                                                     \
    const unsigned short* srcc = wgA + (size_t)(c) * 8192;                     \
    _Pragma("unroll")                                                          \
    for (int q = 0; q < 4; ++q)                                                \
        gload_lds16(srcc + q * 2048 + tid * 8, &lA[buf][q * 2048 + tid * 8]);  \
} while (0)

    // cvt + 32 MFMA on chunk whose B regs are in br and A panel in lA[buf]
#define COMPUTE(br, buf) do {                                                  \
    _Pragma("unroll")                                                          \
    for (int kk = 0; kk < 2; ++kk) {                                           \
        short8 af[8];                                                          \
        _Pragma("unroll")                                                      \
        for (int m = 0; m < 8; ++m) {                                          \
            int o = m * 16 + l15;                                              \
            int slot = (lg + 4 * kk) ^ (o & 7);                                \
            af[m] = *(const short8*)&lA[buf][o * 64 + slot * 8];               \
        }                                                                      \
        _Pragma("unroll")                                                      \
        for (int nf = 0; nf < 2; ++nf) {                                       \
            short8 bf;                                                         \
            _Pragma("unroll")                                                  \
            for (int j = 0; j < 4; ++j) {                                      \
                float2 v = br[kk * 8 + nf * 4 + j];                            \
                bf[2 * j]     = (short)f2bf(v.x);                              \
                bf[2 * j + 1] = (short)f2bf(v.y);                              \
            }                                                                  \
            _Pragma("unroll")                                                  \
            for (int m = 0; m < 8; ++m)                                        \
                acc[m][nf] = __builtin_amdgcn_mfma_f32_16x16x32_bf16(          \
                    af[m], bf, acc[m][nf], 0, 0, 0);                           \
        }                                                                      \
    }                                                                          \
} while (0)

    LOADB(c0, bA);
    STAGE(c0, 0);
    __syncthreads();
    for (int ci = 0; ci < nch; ci += 2) {
        int c = c0 + ci;
        if (ci + 1 < nch) { LOADB(c + 1, bB); STAGE(c + 1, 1); }
        COMPUTE(bA, 0);
        __syncthreads();
        if (ci + 1 < nch) {
            if (ci + 2 < nch) { LOADB(c + 2, bA); STAGE(c + 2, 0); }
            COMPUTE(bB, 1);
            __syncthreads();
        }
    }
#undef LOADB
#undef STAGE
#undef COMPUTE

    if (band == 30) {
        // raw partial write: part[((split*8+b)*4+tti)][o][tloc]
        float* pp = part + (((size_t)blockIdx.y * 8 + b) * 4 + tti) * 16384;
#pragma unroll
        for (int m = 0; m < 8; ++m)
#pragma unroll
            for (int r = 0; r < 4; ++r) {
                int o = m * 16 + lg * 4 + r;
#pragma unroll
                for (int nf = 0; nf < 2; ++nf)
                    pp[o * 128 + wv * 32 + nf * 16 + l15] = acc[m][nf][r];
            }
        return;
    }

    // inline finalize: reduce this (b,band)'s partials (<=4 chunks x 2 cc)
    float sum = 0.f, sq = 0.f;
    {
        int cc0 = c_cumf[band], cc1 = c_cumf[band + 1];
        for (int c = cc0; c < cc1; ++c) {
            const float* p0 = st + (size_t)(c * 16 + b * 2) * 2;
            sum += p0[0] + p0[2];
            sq  += p0[1] + p0[3];
        }
    }
    const float Nf = (float)(w * 2048);    // 4*w*512
    const float mu = sum / Nf;
    const float rs = rsqrtf(sq / Nf - mu * mu + EPSV);

#pragma unroll
    for (int m = 0; m < 8; ++m) {
#pragma unroll
        for (int r = 0; r < 4; ++r) {
            int o = m * 16 + lg * 4 + r;
            float wg = wgam[band * OUTC + o];
            float cb = wcb[band * OUTC + o];
            size_t rowoff = (((size_t)b * OUTC + o) * NBANDS + band) * TTS;
#pragma unroll
            for (int nf = 0; nf < 2; ++nf) {
                int t = tt0 + wv * 32 + nf * 16 + l15;
                out[rowoff + t] = rs * (acc[m][nf][r] - mu * wg) + cb;
            }
        }
    }
}

// ---------------- band-30 split reduction + fused norm epilogue ----------------
// grid 32 (= 8b x 4 ttile), 256 threads; sums 5 partials, applies norm, writes out
__global__ __launch_bounds__(256) void reduce30(const float* __restrict__ st,
                                                const float* __restrict__ wgam,
                                                const float* __restrict__ wcb,
                                                const float* __restrict__ part,
                                                float* __restrict__ out) {
    const int b   = blockIdx.x >> 2;
    const int tti = blockIdx.x & 3;
    const int tid = threadIdx.x;

    // mu/rs for (b, 30): chunks 66..78, cc 0..1
    float sum = 0.f, sq = 0.f;
    for (int c = 66; c < 79; ++c) {
        const float* p0 = st + (size_t)(c * 16 + b * 2) * 2;
        sum += p0[0] + p0[2];
        sq  += p0[1] + p0[3];
    }
    const float Nf = 399.f * 2048.f;
    const float mu = sum / Nf;
    const float rs = rsqrtf(sq / Nf - mu * mu + EPSV);

    const f32x4* p4 = (const f32x4*)part;
    const size_t sl = ((size_t)b * 4 + tti) * 4096;   // per-split vec4 slice base
#pragma unroll
    for (int i = 0; i < 16; ++i) {
        int v = i * 256 + tid;            // 0..4095
        int o = v >> 5;
        int tv = v & 31;
        f32x4 a = p4[sl + v];
        a += p4[1 * 32 * 4096 + sl + v];
        a += p4[2 * 32 * 4096 + sl + v];
        a += p4[3 * 32 * 4096 + sl + v];
        a += p4[4 * 32 * 4096 + sl + v];
        float wg = wgam[30 * OUTC + o];
        float cb = wcb[30 * OUTC + o];
        f32x4 y;
#pragma unroll
        for (int q = 0; q < 4; ++q) y[q] = rs * (a[q] - mu * wg) + cb;
        *(f32x4*)&out[(((size_t)b * OUTC + o) * NBANDS + 30) * TTS + tti * 128 + tv * 4] = y;
    }
}

extern "C" void kernel_launch(void* const* d_in, const int* in_sizes, int n_in,
                              void* d_out, int out_size, void* d_ws, size_t ws_size,
                              hipStream_t stream) {
    const float* x     = (const float*)d_in[0];
    const float* gamma = (const float*)d_in[1];
    const float* beta  = (const float*)d_in[2];
    const float* W     = (const float*)d_in[3];
    const float* bias  = (const float*)d_in[4];
    float* out = (float*)d_out;
    float* ws  = (float*)d_ws;

    float* st_part = ws;            // 79*16*2 = 2528 floats (fully rewritten every call)
    float* wgam    = ws + 3072;     // 3968 floats
    float* wcb     = ws + 7168;     // 3968 floats
    unsigned short* wgP = (unsigned short*)(ws + 11264);  // 1220608 bf16 = 2.33 MB
    float* part    = ws + 622592;   // 5*32*16384 = 2621440 floats = 10.5 MB

    prep<<<NSTATS + NWPREP + NWP2, 256, 0, stream>>>(x, W, gamma, beta, bias,
                                                     st_part, wgam, wcb, wgP);
    gemm_mfma<<<dim3(32, NGY), 256, 0, stream>>>(x, wgP, st_part, wgam, wcb, part, out);
    reduce30<<<32, 256, 0, stream>>>(st_part, wgam, wcb, part, out);
}

// Round 11
// 98.092 us; speedup vs baseline: 1.6894x; 1.0639x over previous
//
#include <hip/hip_runtime.h>
#include <hip/hip_bf16.h>

typedef __attribute__((ext_vector_type(8))) short short8;
typedef __attribute__((ext_vector_type(4))) float f32x4;

#define NBANDS 31
#define BB 8
#define CCH 2
#define FF 2049
#define TTS 512
#define OUTC 128
#define TCH 8196
#define EPSV 1e-5f
#define NTILES 298   // total 32k-tiles across bands

__constant__ int c_wid[NBANDS] = {
    25,25,25,25,25,25,25,25,25,25,
    50,50,50,50,50,50,50,50,50,50,50,50,
    100,100,100,100,100,100,100,100,
    399};
__constant__ int c_start[NBANDS] = {
    0,25,50,75,100,125,150,175,200,225,
    250,300,350,400,450,500,550,600,650,700,750,800,
    850,950,1050,1150,1250,1350,1450,1550,
    1650};
__constant__ int c_cumf[NBANDS + 1] = {
    0,1,2,3,4,5,6,7,8,9,
    10,12,14,16,18,20,22,24,26,28,30,32,
    34,38,42,46,50,54,58,62,
    66,79};
// K padded to multiple of 64 (= 32 * tiles-per-band)
__constant__ int c_kpad[NBANDS] = {
    128,128,128,128,128,128,128,128,128,128,
    256,256,256,256,256,256,256,256,256,256,256,256,
    448,448,448,448,448,448,448,448,
    1600};
// element base of each band's packed (swizzled, chunk-major) Wgamma panel
__constant__ int c_kbase[NBANDS] = {
    0,16384,32768,49152,65536,81920,98304,114688,131072,147456,
    163840,196608,229376,262144,294912,327680,360448,393216,425984,458752,491520,524288,
    557056,614400,671744,729088,786432,843776,901120,958464,
    1015808};
// cumulative tile base per band (tiles of 32 k)
__constant__ int tb16b[NBANDS] = {
    0,4,8,12,16,20,24,28,32,36,
    40,48,56,64,72,80,88,96,104,112,120,128,
    136,150,164,178,192,206,220,234,
    248};
// heavy-first dispatch order (descending K)
__constant__ int c_order[NBANDS] = {
    30,22,23,24,25,26,27,28,29,
    10,11,12,13,14,15,16,17,18,19,20,21,
    0,1,2,3,4,5,6,7,8,9};

#define NSTATS 1264   // 79 chunks x 16 (b,cc)
#define NWPREP 248    // 31 bands x 8 o-groups
#define NWP2   992    // 31 bands x 32

__device__ inline unsigned short f2bf(float f) {
    __hip_bfloat16 h = __float2bfloat16(f);
    unsigned short u;
    __builtin_memcpy(&u, &h, 2);
    return u;
}

__device__ inline void gload_lds16(const void* g, void* l) {
    __builtin_amdgcn_global_load_lds((const __attribute__((address_space(1))) void*)g,
                                     (__attribute__((address_space(3))) void*)l, 16, 0, 0);
}

// ---- fused prep: x transpose-to-bf16-tiles + stats | wgam/wcb | packed A panels ----
// k-permutation (consistent A & B): tile tau = fb*2 + cc (fb = f>>4), klocal = (f&15)*2 + ri
__global__ __launch_bounds__(256) void prep(const float* __restrict__ x,
                                            const float* __restrict__ W,
                                            const float* __restrict__ gamma,
                                            const float* __restrict__ beta,
                                            const float* __restrict__ bias,
                                            float* __restrict__ st,
                                            float* __restrict__ wgam,
                                            float* __restrict__ wcb,
                                            unsigned short* __restrict__ wgP,
                                            unsigned short* __restrict__ xb16) {
    __shared__ float s1[256], s2[256];
    const int bid = blockIdx.x;
    const int tid = threadIdx.x;

    if (bid < NSTATS) {
        // ---- transpose + stats role: one block per (32-f chunk, b, cc) ----
        int bx  = bid >> 4;              // chunk id [0,79)
        int ycc = bid & 15;              // (b<<1)|cc
        int band = 0;
        while (band + 1 < NBANDS && bx >= c_cumf[band + 1]) band++;
        int fc = bx - c_cumf[band];
        int b  = ycc >> 1;
        int cc = ycc & 1;
        int w = c_wid[band], s = c_start[band];
        int nfb = (w + 15) >> 4;
        int fb0 = fc * 2;
        int nfbl = min(2, nfb - fb0);

        int lane = tid & 63, l15 = lane & 15, lg = lane >> 4;
        int tquad = tid >> 6;            // 4 tiles processed concurrently
        const float* xcc = x + (size_t)(b * CCH + cc) * FF * 1024;

        float sum = 0.f, sq = 0.f;
        int ntg = nfbl * 8;              // tile groups of 4 (nfbl*32 tiles total)
        for (int tg = 0; tg < ntg; ++tg) {
            int tile = tg * 4 + tquad;
            int tb = tile & 31, fbl = tile >> 5;
            int fb = fb0 + fbl;
            int t = tb * 16 + l15;
            short8 v8;
#pragma unroll
            for (int rr = 0; rr < 4; ++rr) {
                int f = fb * 16 + 4 * lg + rr;
                float2 v = make_float2(0.f, 0.f);
                if (f < w)
                    v = *(const float2*)(xcc + (size_t)(s + f) * 1024 + t * 2);
                sum += v.x + v.y;
                sq  += v.x * v.x + v.y * v.y;
                v8[2 * rr]     = (short)f2bf(v.x);
                v8[2 * rr + 1] = (short)f2bf(v.y);
            }
            int taug = tb16b[band] + fb * 2 + cc;
            *(short8*)(xb16 + (((size_t)b * NTILES + taug) * 32 + tb) * 512 + lane * 8) = v8;
        }
        s1[tid] = sum; s2[tid] = sq;
        __syncthreads();
        for (int st_ = 128; st_ > 0; st_ >>= 1) {
            if (tid < st_) { s1[tid] += s1[tid + st_]; s2[tid] += s2[tid + st_]; }
            __syncthreads();
        }
        if (tid == 0) {
            float* dst = st + (size_t)(bx * 16 + ycc) * 2;
            dst[0] = s1[0];
            dst[1] = s2[0];
        }
    } else if (bid < NSTATS + NWPREP) {
        // ---- wprep role: wgam/wcb reductions ----
        int r = bid - NSTATS;
        int band = r >> 3;
        int off = 4 * c_start[band];
        int ch  = 4 * c_wid[band];
        int o = (r & 7) * 16 + (tid >> 4);
        int lane = tid & 15;
        const float* wrow = W + (size_t)o * TCH + off;
        float sg = 0.f, sb = 0.f;
        for (int c = lane; c < ch; c += 16) {
            float wv = wrow[c];
            sg += wv * gamma[off + c];
            sb += wv * beta[off + c];
        }
        for (int m = 8; m; m >>= 1) {
            sg += __shfl_down(sg, m, 16);
            sb += __shfl_down(sb, m, 16);
        }
        if (lane == 0) {
            wgam[band * OUTC + o] = sg;
            wcb[band * OUTC + o]  = sb + bias[band * OUTC + o];
        }
    } else {
        // ---- wprep2 role: pack W*gamma bf16 panels, chunk-major, slot-XOR swizzled,
        // NEW k-map: tau=k>>5, fb=tau>>1, cc=tau&1, fo=(k&31)>>1, ri=k&1, f=fb*16+fo ----
        int r = bid - (NSTATS + NWPREP);
        int band = r % NBANDS;
        int gy   = r / NBANDS;           // 0..31
        int w = c_wid[band];
        int s4 = 4 * c_start[band];
        int Kpad = c_kpad[band];
        int base = c_kbase[band];
        int N = OUTC * Kpad;
        for (int idx = gy * 256 + tid; idx < N; idx += 32 * 256) {
            int o = idx / Kpad;
            int k = idx - o * Kpad;
            int tau = k >> 5, fb = tau >> 1, cc = tau & 1;
            int fo = (k & 31) >> 1, ri = k & 1;
            int f = fb * 16 + fo;
            float val = 0.f;
            if (f < w) {
                int c = s4 + ri * 2 * w + cc * w + f;
                val = W[(size_t)o * TCH + c] * gamma[c];
            }
            int slot = (k >> 3) & 7;
            int pos = (k >> 6) * 8192 + o * 64 + ((slot ^ (o & 7)) * 8) + (k & 7);
            wgP[base + pos] = f2bf(val);
        }
    }
}

// ---------------- MFMA GEMM: Y[o,t] = Wg[o,:]*h[:,t], norm fused in epilogue ----------------
// grid (32 = 8b x 4 ttile, 31 bands), 256 threads = 4 waves, each wave: M=128 x N=32.
// B = one lane-contiguous dwordx4 per (chunk,kk,nf) from pre-transposed bf16 tiles (no cvt);
// A via global_load_lds double-buffer (R6-proven loop shape).
__global__ __launch_bounds__(256) void gemm_mfma(const unsigned short* __restrict__ xb16,
                                                 const unsigned short* __restrict__ wgP,
                                                 const float* __restrict__ st,
                                                 const float* __restrict__ wgam,
                                                 const float* __restrict__ wcb,
                                                 float* __restrict__ out) {
    const int band = c_order[blockIdx.y];
    const int b    = blockIdx.x >> 2;
    const int tti  = blockIdx.x & 3;
    const int tt0  = tti * 128;
    const int w    = c_wid[band];
    const int nch  = c_kpad[band] >> 6;
    const unsigned short* wgA = wgP + c_kbase[band];

    __shared__ unsigned short lA[2][8192];   // 2 x 16KB: [o=128][k=64], slot-swizzled

    const int tid  = threadIdx.x;
    const int lane = tid & 63;
    const int wv   = tid >> 6;          // wave id (0..3) -> t-block of 32
    const int l15  = lane & 15;
    const int lg   = lane >> 4;         // 0..3

    // per-lane B base: tiles [b][tau][tb=32][lane][8]; this block/wave covers tb = tti*8+wv*2+nf
    const unsigned short* xbT = xb16 +
        (((size_t)b * NTILES + tb16b[band]) * 32 + tti * 8 + wv * 2) * 512 + lane * 8;

    f32x4 acc[8][2] = {};
    short8 bA[4], bB[4];

    // 4 dwordx4 loads of chunk c's B fragments
#define LOADB(c, dst) do {                                                     \
    _Pragma("unroll")                                                          \
    for (int kk = 0; kk < 2; ++kk)                                             \
        _Pragma("unroll")                                                      \
        for (int nf = 0; nf < 2; ++nf)                                         \
            dst[kk * 2 + nf] =                                                 \
                *(const short8*)(xbT + (size_t)((2 * (c) + kk) * 32 + nf) * 512); \
} while (0)

    // stage chunk c's A panel into LDS buffer buf (16KB via global_load_lds dwordx4)
#define STAGE(c, buf) do {                                                     \
    const unsigned short* srcc = wgA + (size_t)(c) * 8192;                     \
    _Pragma("unroll")                                                          \
    for (int q = 0; q < 4; ++q)                                                \
        gload_lds16(srcc + q * 2048 + tid * 8, &lA[buf][q * 2048 + tid * 8]);  \
} while (0)

    // 32 MFMA on chunk whose B frags are in br and A panel in lA[buf]
#define COMPUTE(br, buf) do {                                                  \
    _Pragma("unroll")                                                          \
    for (int kk = 0; kk < 2; ++kk) {                                           \
        short8 af[8];                                                          \
        _Pragma("unroll")                                                      \
        for (int m = 0; m < 8; ++m) {                                          \
            int o = m * 16 + l15;                                              \
            int slot = (lg + 4 * kk) ^ (o & 7);                                \
            af[m] = *(const short8*)&lA[buf][o * 64 + slot * 8];               \
        }                                                                      \
        _Pragma("unroll")                                                      \
        for (int nf = 0; nf < 2; ++nf)                                         \
            _Pragma("unroll")                                                  \
            for (int m = 0; m < 8; ++m)                                        \
                acc[m][nf] = __builtin_amdgcn_mfma_f32_16x16x32_bf16(          \
                    af[m], br[kk * 2 + nf], acc[m][nf], 0, 0, 0);              \
    }                                                                          \
} while (0)

    LOADB(0, bA);
    STAGE(0, 0);
    __syncthreads();
    for (int c = 0; c < nch; c += 2) {
        if (c + 1 < nch) { LOADB(c + 1, bB); STAGE(c + 1, 1); }
        COMPUTE(bA, 0);
        __syncthreads();
        if (c + 1 < nch) {
            if (c + 2 < nch) { LOADB(c + 2, bA); STAGE(c + 2, 0); }
            COMPUTE(bB, 1);
            __syncthreads();
        }
    }
#undef LOADB
#undef STAGE
#undef COMPUTE

    // inline finalize: reduce this (b,band)'s stats partials
    float sum = 0.f, sq = 0.f;
    {
        int cc0 = c_cumf[band], cc1 = c_cumf[band + 1];
        for (int c = cc0; c < cc1; ++c) {
            const float* p0 = st + (size_t)(c * 16 + b * 2) * 2;
            sum += p0[0] + p0[2];
            sq  += p0[1] + p0[3];
        }
    }
    const float Nf = (float)(w * 2048);    // 4*w*512
    const float mu = sum / Nf;
    const float rs = rsqrtf(sq / Nf - mu * mu + EPSV);

#pragma unroll
    for (int m = 0; m < 8; ++m) {
#pragma unroll
        for (int r = 0; r < 4; ++r) {
            int o = m * 16 + lg * 4 + r;
            float wg = wgam[band * OUTC + o];
            float cb = wcb[band * OUTC + o];
            size_t rowoff = (((size_t)b * OUTC + o) * NBANDS + band) * TTS;
#pragma unroll
            for (int nf = 0; nf < 2; ++nf) {
                int t = tt0 + wv * 32 + nf * 16 + l15;
                out[rowoff + t] = rs * (acc[m][nf][r] - mu * wg) + cb;
            }
        }
    }
}

extern "C" void kernel_launch(void* const* d_in, const int* in_sizes, int n_in,
                              void* d_out, int out_size, void* d_ws, size_t ws_size,
                              hipStream_t stream) {
    const float* x     = (const float*)d_in[0];
    const float* gamma = (const float*)d_in[1];
    const float* beta  = (const float*)d_in[2];
    const float* W     = (const float*)d_in[3];
    const float* bias  = (const float*)d_in[4];
    float* out = (float*)d_out;
    float* ws  = (float*)d_ws;

    float* st_part = ws;            // 2528 floats (fully rewritten every call)
    float* wgam    = ws + 3072;     // 3968 floats
    float* wcb     = ws + 7168;     // 3968 floats
    unsigned short* wgP  = (unsigned short*)(ws + 11264);   // 1,220,608 bf16 = 2.33 MB
    unsigned short* xb16 = (unsigned short*)(ws + 622592);  // 39,059,456 bf16 = 74.5 MB

    prep<<<NSTATS + NWPREP + NWP2, 256, 0, stream>>>(x, W, gamma, beta, bias,
                                                     st_part, wgam, wcb, wgP, xb16);
    gemm_mfma<<<dim3(32, NBANDS), 256, 0, stream>>>(xb16, wgP, st_part, wgam, wcb, out);
}